// Round 12
// baseline (293.241 us; speedup 1.0000x reference)
//
#include <hip/hip_runtime.h>
#include <hip/hip_bf16.h>

#define DIM 128
#define PCH 4096        // edges per partition block (LDS-staged)
#define CAP 8192        // build: LDS edge-staging capacity (expected ~4096/block)
#define SHIFT_F 8       // fine bucket: 256 nodes (build block granularity)
#define SHIFT_C 11      // coarse bucket: 2048 nodes (partition write granularity)
#define FPC 8           // fine per coarse = 1 << (SHIFT_C - SHIFT_F)

typedef __attribute__((ext_vector_type(8))) short bf16x8;
typedef __attribute__((ext_vector_type(4))) float f32x4;

__device__ __forceinline__ float bfu_lo(unsigned u) { return __uint_as_float(u << 16); }
__device__ __forceinline__ float bfu_hi(unsigned u) { return __uint_as_float(u & 0xffff0000u); }
__device__ __forceinline__ unsigned short f2bf(float f) {
    unsigned u = __float_as_uint(f);
    u += 0x7fffu + ((u >> 16) & 1u);   // round-to-nearest-even
    return (unsigned short)(u >> 16);
}

__device__ __forceinline__ int edge_at(const void* ei, int idx64, long long pos) {
    return idx64 ? (int)__builtin_nontemporal_load((const long long*)ei + pos)
                 : __builtin_nontemporal_load((const int*)ei + pos);
}

// Block-local edge-width sniff: 1 iff int64 (high halves of first 4096 all 0).
__device__ __forceinline__ int detect_idx64(const void* ei, int E, unsigned* s_or, int* s_flag) {
    const unsigned* ei_w = (const unsigned*)ei;
    int t = threadIdx.x;
    unsigned o = 0;
    int lim = (E < 4096) ? E : 4096;
    for (int k = t; k < lim; k += 256) o |= ei_w[2 * k + 1];
    s_or[t] = o;
    __syncthreads();
    for (int s = 128; s > 0; s >>= 1) {
        if (t < s) s_or[t] |= s_or[t + s];
        __syncthreads();
    }
    if (t == 0) *s_flag = (s_or[0] == 0u) ? 1 : 0;
    __syncthreads();
    return *s_flag;
}

// Histogram of destinations over COARSE buckets (Bc <= 64). Fused width
// detect; block 0 publishes the flag. bcnt pre-zeroed (memset).
__global__ __launch_bounds__(256) void hist_detect(const void* ei, unsigned* bcnt,
                                                   int* flags, int E) {
    __shared__ unsigned s_h[64];
    __shared__ unsigned s_or[256];
    __shared__ int s_flag;
    int t = threadIdx.x;
    if (t < 64) s_h[t] = 0u;
    int idx64 = detect_idx64(ei, E, s_or, &s_flag);
    if (blockIdx.x == 0 && t == 0) flags[0] = idx64;
    long long stride = (long long)gridDim.x * 256;
    for (long long e = (long long)blockIdx.x * 256 + t; e < E; e += stride) {
        int d = edge_at(ei, idx64, (long long)E + e);
        atomicAdd(&s_h[d >> SHIFT_C], 1u);
    }
    __syncthreads();
    if (t < 64 && s_h[t]) atomicAdd(&bcnt[t], s_h[t]);
}

// LDS-staged partition into COARSE buckets. Key change vs R11: with only
// Bc~49 buckets, each block's flush runs are PCH/Bc ~ 84 edges = 334B --
// full-line coalesced stores -- vs the old 391-bucket variant whose ~5-edge
// (21B) runs were a 4B-granule cross-XCD scatter (the hidden ~50+us).
// Output element is PACKED 32-bit: (d & (2^SHIFT_C-1)) << 21 | src
// (valid while N < 2^21; here N=1e5).
__global__ __launch_bounds__(256) void partition(const void* ei, const int* __restrict__ flags,
                                                 const unsigned* __restrict__ bcnt,
                                                 unsigned* bcur0, unsigned* pout,
                                                 int E, int Bc) {
    __shared__ unsigned s_hist[64], s_off[64], s_gbase[64], s_pref[64], s_bbase[64];
    __shared__ unsigned d_arr[PCH], s_arr[PCH];
    int t = threadIdx.x;
    long long base = (long long)blockIdx.x * PCH;
    if (t < 64) { s_hist[t] = 0u; s_off[t] = 0u; }
    int idx64 = flags[0];

    // single-wave exclusive scan of global coarse counts -> s_bbase
    if (t < 64) {
        unsigned v = (t < Bc) ? bcnt[t] : 0u;
        unsigned s = v;
#pragma unroll
        for (int off = 1; off < 64; off <<= 1) {
            unsigned u = __shfl_up(s, off, 64);
            if (t >= off) s += u;
        }
        s_bbase[t] = s - v;
    }
    __syncthreads();

    // load own edges into registers, LDS coarse histogram
    int d_[PCH / 256], s_[PCH / 256];
#pragma unroll
    for (int j = 0; j < PCH / 256; j++) {
        long long e = base + j * 256 + t;
        if (e < E) {
            d_[j] = edge_at(ei, idx64, (long long)E + e);
            s_[j] = edge_at(ei, idx64, e);
            atomicAdd(&s_hist[d_[j] >> SHIFT_C], 1u);
        } else d_[j] = -1;
    }
    __syncthreads();

    // single-wave exclusive scan of local coarse counts -> s_pref
    if (t < 64) {
        unsigned v = s_hist[t];
        unsigned s = v;
#pragma unroll
        for (int off = 1; off < 64; off <<= 1) {
            unsigned u = __shfl_up(s, off, 64);
            if (t >= off) s += u;
        }
        s_pref[t] = s - v;
    }
    __syncthreads();

    if (t < Bc && s_hist[t])
        s_gbase[t] = s_bbase[t] + atomicAdd(&bcur0[t], s_hist[t]);
#pragma unroll
    for (int j = 0; j < PCH / 256; j++)
        if (d_[j] >= 0) {
            int b = d_[j] >> SHIFT_C;
            unsigned p = s_pref[b] + atomicAdd(&s_off[b], 1u);
            d_arr[p] = (unsigned)d_[j];
            s_arr[p] = (unsigned)s_[j];
        }
    __syncthreads();
    long long rem = (long long)E - base;
    unsigned tot = (rem < PCH) ? (unsigned)rem : (unsigned)PCH;
    unsigned msk = (1u << SHIFT_C) - 1u;
    for (unsigned i = t; i < tot; i += 256) {
        unsigned d = d_arr[i];
        int b = (int)(d >> SHIFT_C);            // direct bucket recompute
        unsigned pk = ((d & msk) << 21) | s_arr[i];
        pout[s_gbase[b] + (i - s_pref[b])] = pk;
    }
}

// One block per FINE bucket (256 nodes), 391 blocks (dense grid -- R8
// lesson). Scans its COARSE segment (8x over-read, ~51MB total, L2-shared
// among the 8 sibling blocks), filters its fine bucket, stages edges in LDS
// (warp-aggregated append), then histogram/scan/CSR-fill entirely in LDS.
// Overflow (staged > CAP) falls back to a global re-scan -- data-robust.
__global__ __launch_bounds__(256) void build_csr(const unsigned* __restrict__ pairs,
                                                 const unsigned* __restrict__ bcnt,
                                                 unsigned* deg, unsigned* row_start,
                                                 float* dis, int* col_src,
                                                 int N, int Bc) {
    __shared__ unsigned cnt[256], cur[256], pref[256];
    __shared__ unsigned s_cb[65];
    __shared__ unsigned s_sib[FPC];
    __shared__ unsigned s_scnt;
    __shared__ unsigned stage[CAP];
    __shared__ unsigned wsum[4];
    int b = blockIdx.x, t = threadIdx.x;
    int g = b >> 3, myfine = b & (FPC - 1);
    int lane = t & 63;

    // single-wave exclusive scan of coarse counts -> coarse segment [lo,hi)
    if (t < 64) {
        unsigned v = (t < Bc) ? bcnt[t] : 0u;
        unsigned s = v;
#pragma unroll
        for (int off = 1; off < 64; off <<= 1) {
            unsigned u = __shfl_up(s, off, 64);
            if (t >= off) s += u;
        }
        s_cb[t] = s - v;
        if (t == 63) s_cb[64] = s;
    }
    cnt[t] = 0u;
    if (t < FPC) s_sib[t] = 0u;
    if (t == 0) s_scnt = 0u;
    __syncthreads();
    unsigned lo = s_cb[g], hi = (g + 1 < 64) ? s_cb[g + 1] : s_cb[64];

    // phase A: scan segment, count siblings + own-node histogram, stage own
    unsigned iters = (hi - lo + 255u) >> 8;
    for (unsigned it = 0; it < iters; ++it) {
        unsigned e = lo + it * 256u + (unsigned)t;
        bool valid = e < hi;
        unsigned p = valid ? pairs[e] : 0u;
        unsigned dlow = p >> 21;                     // SHIFT_C bits of d
        int sib = (int)(dlow >> SHIFT_F);            // which fine sibling
        bool keep = valid && (sib == myfine);
        if (valid) atomicAdd(&s_sib[sib], 1u);
        if (keep) atomicAdd(&cnt[dlow & 255u], 1u);
        unsigned long long mask = __ballot(keep);
        if (mask) {                                  // warp-aggregated append
            int leader = (int)__ffsll((long long)mask) - 1;
            int rank = (int)__popcll(mask & ((1ull << lane) - 1ull));
            unsigned basew = 0;
            if (lane == leader) basew = atomicAdd(&s_scnt, (unsigned)__popcll(mask));
            basew = (unsigned)__shfl((int)basew, leader, 64);
            if (keep && basew + (unsigned)rank < CAP) stage[basew + rank] = p;
        }
    }
    __syncthreads();

    // fine-bucket base in the CSR = coarse base + preceding siblings' counts
    unsigned fbase = lo;
    for (int j = 0; j < myfine; j++) fbase += s_sib[j];

    // exclusive scan of 256 node counts (1/thread, 4 waves)
    unsigned v = cnt[t];
    unsigned s = v;
#pragma unroll
    for (int off = 1; off < 64; off <<= 1) {
        unsigned u = __shfl_up(s, off, 64);
        if (lane >= off) s += u;
    }
    int w = t >> 6;
    if (lane == 63) wsum[w] = s;
    __syncthreads();
    unsigned woff = 0;
    for (int j = 0; j < w; j++) woff += wsum[j];
    pref[t] = woff + s - v;
    __syncthreads();

    int node = (b << SHIFT_F) + t;
    unsigned rs = fbase + pref[t];
    if (node < N) {
        unsigned c = cnt[t];
        deg[node] = c;
        row_start[node] = rs;
        dis[node] = rsqrtf((float)c + 1.0f);         // +1 self-loop
    }
    cur[t] = rs;
    __syncthreads();

    unsigned total = s_scnt;
    if (total <= CAP) {
        for (unsigned k = t; k < total; k += 256) {
            unsigned p = stage[k];
            unsigned n8 = (p >> 21) & 255u;
            unsigned pos = atomicAdd(&cur[n8], 1u);
            col_src[pos] = (int)(p & 0x1FFFFFu);
        }
    } else {
        // robust slow path: re-scan segment from global (never for random data)
        for (unsigned e = lo + t; e < hi; e += 256) {
            unsigned p = pairs[e];
            unsigned dlow = p >> 21;
            if ((int)(dlow >> SHIFT_F) == myfine) {
                unsigned pos = atomicAdd(&cur[dlow & 255u], 1u);
                col_src[pos] = (int)(p & 0x1FFFFFu);
            }
        }
    }
}

// xps = dis[row] * (x @ W), bf16 MFMA, fp32 x in / packed-bf16 out (pre-scaled).
// W transpose+bf16-convert fused into LDS (padded stride 136 shorts).
// Operand swap: mfma(Wfrag, Xfrag, acc) -> lane holds out[row=rowBase+l15][col=quad*4+reg]
__global__ __launch_bounds__(256) void gemm_xw(const float* __restrict__ x,
                                               const float* __restrict__ W,
                                               const float* __restrict__ dis,
                                               unsigned short* __restrict__ xps, int N) {
    __shared__ unsigned short wt[128 * 136];
    int tid = threadIdx.x;
    for (int idx = tid; idx < DIM * DIM; idx += 256) {
        int k = idx >> 7, n = idx & 127;        // idx = k*128+n -> coalesced W read
        wt[n * 136 + k] = f2bf(W[idx]);
    }
    __syncthreads();

    int wv = tid >> 6, lane = tid & 63;
    int l15 = lane & 15, quad = lane >> 4;
    int rowBase = blockIdx.x * 128 + wv * 32;

    f32x4 acc[2][8];
#pragma unroll
    for (int mt = 0; mt < 2; mt++)
#pragma unroll
        for (int nt = 0; nt < 8; nt++)
            acc[mt][nt] = (f32x4){0.f, 0.f, 0.f, 0.f};

#pragma unroll
    for (int k0 = 0; k0 < DIM; k0 += 32) {
        bf16x8 aa[2], bb[8];
#pragma unroll
        for (int mt = 0; mt < 2; mt++) {
            int r = rowBase + mt * 16 + l15;
            if (r > N - 1) r = N - 1;           // clamp; garbage rows never stored
            const float* xf = x + (size_t)r * DIM + k0 + quad * 8;
            float4 u0 = ((const float4*)xf)[0];
            float4 u1 = ((const float4*)xf)[1];
            bf16x8 a;
            a[0] = (short)f2bf(u0.x); a[1] = (short)f2bf(u0.y);
            a[2] = (short)f2bf(u0.z); a[3] = (short)f2bf(u0.w);
            a[4] = (short)f2bf(u1.x); a[5] = (short)f2bf(u1.y);
            a[6] = (short)f2bf(u1.z); a[7] = (short)f2bf(u1.w);
            aa[mt] = a;
        }
#pragma unroll
        for (int nt = 0; nt < 8; nt++)
            bb[nt] = *(const bf16x8*)(wt + (nt * 16 + l15) * 136 + k0 + quad * 8);
#pragma unroll
        for (int mt = 0; mt < 2; mt++)
#pragma unroll
            for (int nt = 0; nt < 8; nt++)
                acc[mt][nt] = __builtin_amdgcn_mfma_f32_16x16x32_bf16(bb[nt], aa[mt], acc[mt][nt], 0, 0, 0);
    }

#pragma unroll
    for (int mt = 0; mt < 2; mt++) {
        int r = rowBase + mt * 16 + l15;
        if (r < N) {
            float sc = dis[r];                  // pre-scale by source-side dis
#pragma unroll
            for (int nt = 0; nt < 8; nt++) {
                int c0 = nt * 16 + quad * 4;
                ushort4 o;
                o.x = f2bf(acc[mt][nt][0] * sc);
                o.y = f2bf(acc[mt][nt][1] * sc);
                o.z = f2bf(acc[mt][nt][2] * sc);
                o.w = f2bf(acc[mt][nt][3] * sc);
                *(ushort4*)(xps + (size_t)r * DIM + c0) = o;
            }
        }
    }
}

// One wave per node. EXACT R5/R10 form: VGPR=28 -> 8 waves/SIMD; R7 and R9
// ILP variants both regressed -- TLP at max occupancy hides the gather
// latency. Self-loop is virtual slot `cnt`. out[d] = dis[d] * sum(xps).
__global__ __launch_bounds__(256) void aggregate(const unsigned short* __restrict__ xps,
                                                 const unsigned* __restrict__ row_start,
                                                 const unsigned* __restrict__ deg,
                                                 const float* __restrict__ dis,
                                                 const int* __restrict__ col_src,
                                                 float* __restrict__ out, int N) {
    int wid = (int)((blockIdx.x * 256 + threadIdx.x) >> 6);
    if (wid >= N) return;
    int lane = threadIdx.x & 63;
    int grp = lane >> 4, lin = lane & 15;
    const uint4* xp4 = (const uint4*)xps;       // row = 16 x uint4

    float acc[8];
#pragma unroll
    for (int j = 0; j < 8; j++) acc[j] = 0.f;

    unsigned rs = row_start[wid];
    unsigned cnt = deg[wid];
    unsigned tot = cnt + 1;                      // + virtual self slot

    for (unsigned base = 0; base < tot; base += 64) {
        unsigned slot = base + (unsigned)lane;
        int idx = (slot < cnt) ? col_src[rs + slot] : wid;   // invalid/self -> wid (safe)
        unsigned rem = tot - base; if (rem > 64) rem = 64;
        for (unsigned q = 0; q * 8 < rem; q++) {
            unsigned sl0 = q * 8 + (unsigned)grp;
            unsigned sl1 = sl0 + 4;
            int s0 = __shfl(idx, (int)sl0, 64);
            int s1 = __shfl(idx, (int)sl1, 64);
            float m0 = (sl0 < rem) ? 1.f : 0.f;
            float m1 = (sl1 < rem) ? 1.f : 0.f;
            uint4 v0 = xp4[(size_t)s0 * 16 + lin];
            uint4 v1 = xp4[(size_t)s1 * 16 + lin];
            acc[0] = fmaf(bfu_lo(v0.x), m0, acc[0]);
            acc[1] = fmaf(bfu_hi(v0.x), m0, acc[1]);
            acc[2] = fmaf(bfu_lo(v0.y), m0, acc[2]);
            acc[3] = fmaf(bfu_hi(v0.y), m0, acc[3]);
            acc[4] = fmaf(bfu_lo(v0.z), m0, acc[4]);
            acc[5] = fmaf(bfu_hi(v0.z), m0, acc[5]);
            acc[6] = fmaf(bfu_lo(v0.w), m0, acc[6]);
            acc[7] = fmaf(bfu_hi(v0.w), m0, acc[7]);
            acc[0] = fmaf(bfu_lo(v1.x), m1, acc[0]);
            acc[1] = fmaf(bfu_hi(v1.x), m1, acc[1]);
            acc[2] = fmaf(bfu_lo(v1.y), m1, acc[2]);
            acc[3] = fmaf(bfu_hi(v1.y), m1, acc[3]);
            acc[4] = fmaf(bfu_lo(v1.z), m1, acc[4]);
            acc[5] = fmaf(bfu_hi(v1.z), m1, acc[5]);
            acc[6] = fmaf(bfu_lo(v1.w), m1, acc[6]);
            acc[7] = fmaf(bfu_hi(v1.w), m1, acc[7]);
        }
    }

    // reduce across the 4 groups (lanes differing in bits 4 and 5)
#pragma unroll
    for (int j = 0; j < 8; j++) {
        acc[j] += __shfl_xor(acc[j], 16, 64);
        acc[j] += __shfl_xor(acc[j], 32, 64);
    }

    float di = dis[wid];
    if (grp < 2) {                               // 32 lanes store the 512B row
        int jb = (grp & 1) * 4;
        float4 o;
        o.x = acc[jb + 0] * di;
        o.y = acc[jb + 1] * di;
        o.z = acc[jb + 2] * di;
        o.w = acc[jb + 3] * di;
        *(float4*)(out + (size_t)wid * DIM + lin * 8 + jb) = o;
    }
}

extern "C" void kernel_launch(void* const* d_in, const int* in_sizes, int n_in,
                              void* d_out, int out_size, void* d_ws, size_t ws_size,
                              hipStream_t stream) {
    const int N = in_sizes[0] / DIM;
    const int E = in_sizes[1] / 2;
    const float* x = (const float*)d_in[0];                     // fp32 [N][128]
    const void* ei = d_in[1];                                   // int32 or int64 [2][E]
    const float* W = (const float*)d_in[2];                     // fp32 [128][128]
    float* out = (float*)d_out;                                 // fp32 [N][128]

    // Geometry: coarse = 2048 nodes (partition writes, Bc<=64), fine = 256
    // nodes (build blocks, Bf<=512). Valid for N <= 131072; packed 21-bit
    // src requires N < 2^21. This problem: N=100000 -> Bc=49, Bf=391.
    int Bc = (N + (1 << SHIFT_C) - 1) >> SHIFT_C;
    int Bf = (N + (1 << SHIFT_F) - 1) >> SHIFT_F;

    char* wsp = (char*)d_ws;
    size_t off = 0;
    auto alloc = [&](size_t b) { void* p = wsp + off; off += (b + 255) & ~(size_t)255; return p; };
    unsigned* bcnt       = (unsigned*)alloc(4096);              // [0..63]=bcnt, +512 = bcur0
    unsigned* bcur0      = bcnt + 512;
    int*      flags      = (int*)alloc(256);
    unsigned* deg        = (unsigned*)alloc((size_t)N * 4);
    unsigned* row_start  = (unsigned*)alloc((size_t)N * 4);
    float*    dis        = (float*)alloc((size_t)N * 4);
    int*      col_src    = (int*)alloc((size_t)E * 4);
    unsigned short* xps  = (unsigned short*)alloc((size_t)N * DIM * 2);

    // packed pairs alias the xps region (E*4 = 6.4MB <= N*DIM*2 = 25.6MB):
    // dead before gemm_xw writes xps (stream-ordered), so no extra workspace.
    unsigned* pairs = (unsigned*)xps;
    if ((size_t)E * 4 > (size_t)N * DIM * 2 && off + (size_t)E * 4 <= ws_size)
        pairs = (unsigned*)alloc((size_t)E * 4);

    hipMemsetAsync(bcnt, 0, 4096, stream);
    hist_detect<<<512, 256, 0, stream>>>(ei, bcnt, flags, E);
    partition<<<(E + PCH - 1) / PCH, 256, 0, stream>>>(ei, flags, bcnt, bcur0, pairs, E, Bc);
    build_csr<<<Bf, 256, 0, stream>>>(pairs, bcnt, deg, row_start, dis, col_src, N, Bc);
    gemm_xw<<<(N + 127) / 128, 256, 0, stream>>>(x, W, dis, xps, N);
    aggregate<<<(N + 3) / 4, 256, 0, stream>>>(xps, row_start, deg, dis, col_src, out, N);
}

// Round 13
// 250.007 us; speedup vs baseline: 1.1729x; 1.1729x over previous
//
#include <hip/hip_runtime.h>
#include <hip/hip_bf16.h>

#define DIM 128
#define PCH1 4096       // edges per pass-1 partition block
#define PCH2 2048       // edges per pass-2 partition block
#define SHIFT_C 11      // coarse bucket: 2048 nodes (pass-1 write granularity)
#define SHIFT_F 8       // fine bucket: 256 nodes (pass-2 / build granularity)

typedef __attribute__((ext_vector_type(8))) short bf16x8;
typedef __attribute__((ext_vector_type(4))) float f32x4;

__device__ __forceinline__ float bfu_lo(unsigned u) { return __uint_as_float(u << 16); }
__device__ __forceinline__ float bfu_hi(unsigned u) { return __uint_as_float(u & 0xffff0000u); }
__device__ __forceinline__ unsigned short f2bf(float f) {
    unsigned u = __float_as_uint(f);
    u += 0x7fffu + ((u >> 16) & 1u);   // round-to-nearest-even
    return (unsigned short)(u >> 16);
}

__device__ __forceinline__ int edge_at(const void* ei, int idx64, long long pos) {
    return idx64 ? (int)__builtin_nontemporal_load((const long long*)ei + pos)
                 : __builtin_nontemporal_load((const int*)ei + pos);
}

// Block-local edge-width sniff: 1 iff int64 (high halves of first 4096 all 0).
__device__ __forceinline__ int detect_idx64(const void* ei, int E, unsigned* s_or, int* s_flag) {
    const unsigned* ei_w = (const unsigned*)ei;
    int t = threadIdx.x;
    unsigned o = 0;
    int lim = (E < 4096) ? E : 4096;
    for (int k = t; k < lim; k += 256) o |= ei_w[2 * k + 1];
    s_or[t] = o;
    __syncthreads();
    for (int s = 128; s > 0; s >>= 1) {
        if (t < s) s_or[t] |= s_or[t + s];
        __syncthreads();
    }
    if (t == 0) *s_flag = (s_or[0] == 0u) ? 1 : 0;
    __syncthreads();
    return *s_flag;
}

// FINE (512-entry) histogram of destinations + fused width detect (block 0
// publishes flag). Per-edge increments hit LDS over 512 words (proven
// dilution); global atomics only per-block flush. bcnt pre-zeroed.
__global__ __launch_bounds__(256) void hist_detect(const void* ei, unsigned* bcnt,
                                                   int* flags, int E) {
    __shared__ unsigned s_h[512];
    __shared__ unsigned s_or[256];
    __shared__ int s_flag;
    int t = threadIdx.x;
    for (int i = t; i < 512; i += 256) s_h[i] = 0u;
    int idx64 = detect_idx64(ei, E, s_or, &s_flag);
    if (blockIdx.x == 0 && t == 0) flags[0] = idx64;
    long long stride = (long long)gridDim.x * 256;
    for (long long e = (long long)blockIdx.x * 256 + t; e < E; e += stride) {
        int d = edge_at(ei, idx64, (long long)E + e);
        atomicAdd(&s_h[d >> SHIFT_F], 1u);
    }
    __syncthreads();
    for (int i = t; i < 512; i += 256)
        if (s_h[i]) atomicAdd(&bcnt[i], s_h[i]);
}

// PASS 1: partition raw edges into COARSE buckets (Bc<=64, 2048 nodes each).
// Flush runs = PCH1/Bc ~ 84 edges = 336B full-line stores (R12-proven fast).
// Output PACKED 32-bit: (d & 2047) << 21 | src   (needs N < 2^21).
__global__ __launch_bounds__(256) void partition1(const void* ei, const int* __restrict__ flags,
                                                  const unsigned* __restrict__ bcnt,
                                                  unsigned* bcur_c, unsigned* pout, int E) {
    __shared__ unsigned s_hist[64], s_off[64], s_gbase[64], s_pref[64], s_cbase[64];
    __shared__ unsigned d_arr[PCH1], s_arr[PCH1];
    int t = threadIdx.x;
    long long base = (long long)blockIdx.x * PCH1;
    if (t < 64) { s_hist[t] = 0u; s_off[t] = 0u; }
    int idx64 = flags[0];

    // coarse bases from fine bcnt: t<64 sums its 8 fine counts, wave-scans
    if (t < 64) {
        unsigned v = 0;
#pragma unroll
        for (int j = 0; j < 8; j++) v += bcnt[t * 8 + j];
        unsigned s = v;
#pragma unroll
        for (int off = 1; off < 64; off <<= 1) {
            unsigned u = __shfl_up(s, off, 64);
            if (t >= off) s += u;
        }
        s_cbase[t] = s - v;
    }
    __syncthreads();

    int d_[PCH1 / 256], s_[PCH1 / 256];
#pragma unroll
    for (int j = 0; j < PCH1 / 256; j++) {
        long long e = base + j * 256 + t;
        if (e < E) {
            d_[j] = edge_at(ei, idx64, (long long)E + e);
            s_[j] = edge_at(ei, idx64, e);
            atomicAdd(&s_hist[d_[j] >> SHIFT_C], 1u);
        } else d_[j] = -1;
    }
    __syncthreads();

    if (t < 64) {
        unsigned v = s_hist[t];
        unsigned s = v;
#pragma unroll
        for (int off = 1; off < 64; off <<= 1) {
            unsigned u = __shfl_up(s, off, 64);
            if (t >= off) s += u;
        }
        s_pref[t] = s - v;
    }
    __syncthreads();

    if (t < 64 && s_hist[t])
        s_gbase[t] = s_cbase[t] + atomicAdd(&bcur_c[t], s_hist[t]);
#pragma unroll
    for (int j = 0; j < PCH1 / 256; j++)
        if (d_[j] >= 0) {
            int b = d_[j] >> SHIFT_C;
            unsigned p = s_pref[b] + atomicAdd(&s_off[b], 1u);
            d_arr[p] = (unsigned)d_[j];
            s_arr[p] = (unsigned)s_[j];
        }
    __syncthreads();
    long long rem = (long long)E - base;
    unsigned tot = (rem < PCH1) ? (unsigned)rem : (unsigned)PCH1;
    unsigned msk = (1u << SHIFT_C) - 1u;
    for (unsigned i = t; i < tot; i += 256) {
        unsigned d = d_arr[i];
        int b = (int)(d >> SHIFT_C);            // direct bucket recompute
        pout[s_gbase[b] + (i - s_pref[b])] = ((d & msk) << 21) | s_arr[i];
    }
}

// PASS 2: split the coarse-sorted stream into FINE buckets (256 nodes).
// A block's PCH2=2048 edges live in <=2 coarse buckets, so per-fine flush
// runs are ~PCH2/16..PCH2/8 = 128-256 edges = 512B-1KB full-line stores.
// Coarse id recovered from POSITION (monotone walk over s_cb boundaries);
// per-edge LDS hist over 512 words (proven dilution, no 8-word hotspot).
__global__ __launch_bounds__(256) void partition2(const unsigned* __restrict__ pin,
                                                  const unsigned* __restrict__ bcnt,
                                                  unsigned* bcur_f, unsigned* pout, int E) {
    __shared__ unsigned s_cb[65];
    __shared__ unsigned s_fb[512];
    __shared__ unsigned s_hist[512], s_off[512], s_gbase[512], s_pref[512];
    __shared__ unsigned wsum[4];
    __shared__ unsigned pk[PCH2];
    __shared__ unsigned short f9[PCH2];
    int t = threadIdx.x;
    long long base = (long long)blockIdx.x * PCH2;
    for (int i = t; i < 512; i += 256) { s_hist[i] = 0u; s_off[i] = 0u; }

    // coarse boundaries (for position->coarse walk)
    if (t < 64) {
        unsigned v = 0;
#pragma unroll
        for (int j = 0; j < 8; j++) v += bcnt[t * 8 + j];
        unsigned s = v;
#pragma unroll
        for (int off = 1; off < 64; off <<= 1) {
            unsigned u = __shfl_up(s, off, 64);
            if (t >= off) s += u;
        }
        s_cb[t] = s - v;
        if (t == 63) s_cb[64] = s;              // = E
    }
    // fine bases (global, 512-entry scan, 2/thread)
    {
        unsigned v0 = bcnt[2 * t], v1 = bcnt[2 * t + 1];
        unsigned ps = v0 + v1;
        unsigned s = ps;
        int lane = t & 63;
#pragma unroll
        for (int off = 1; off < 64; off <<= 1) {
            unsigned u = __shfl_up(s, off, 64);
            if (lane >= off) s += u;
        }
        int w = t >> 6;
        if (lane == 63) wsum[w] = s;
        __syncthreads();
        unsigned woff = 0;
        for (int j = 0; j < w; j++) woff += wsum[j];
        unsigned excl = woff + s - ps;
        s_fb[2 * t] = excl;
        s_fb[2 * t + 1] = excl + v0;
    }
    __syncthreads();

    unsigned p_[PCH2 / 256];
    int f_[PCH2 / 256];
    int c = 0;
#pragma unroll
    for (int j = 0; j < PCH2 / 256; j++) {
        long long e = base + j * 256 + t;
        if (e < E) {
            while (e >= (long long)s_cb[c + 1]) c++;   // monotone; sentinel s_cb[64]=E
            unsigned p = pin[e];
            p_[j] = p;
            f_[j] = c * 8 + (int)(p >> 29);            // global fine bucket
            atomicAdd(&s_hist[f_[j]], 1u);
        } else f_[j] = -1;
    }
    __syncthreads();

    // local fine scan (512)
    {
        unsigned v0 = s_hist[2 * t], v1 = s_hist[2 * t + 1];
        unsigned ps = v0 + v1;
        unsigned s = ps;
        int lane = t & 63;
#pragma unroll
        for (int off = 1; off < 64; off <<= 1) {
            unsigned u = __shfl_up(s, off, 64);
            if (lane >= off) s += u;
        }
        int w = t >> 6;
        if (lane == 63) wsum[w] = s;
        __syncthreads();
        unsigned woff = 0;
        for (int j = 0; j < w; j++) woff += wsum[j];
        unsigned excl = woff + s - ps;
        s_pref[2 * t] = excl;
        s_pref[2 * t + 1] = excl + v0;
    }
    __syncthreads();

    for (int i = t; i < 512; i += 256)
        if (s_hist[i]) s_gbase[i] = s_fb[i] + atomicAdd(&bcur_f[i], s_hist[i]);
#pragma unroll
    for (int j = 0; j < PCH2 / 256; j++)
        if (f_[j] >= 0) {
            unsigned pp = s_pref[f_[j]] + atomicAdd(&s_off[f_[j]], 1u);
            pk[pp] = p_[j];
            f9[pp] = (unsigned short)f_[j];
        }
    __syncthreads();
    long long rem = (long long)E - base;
    unsigned tot = (rem < PCH2) ? (unsigned)rem : (unsigned)PCH2;
    for (unsigned i = t; i < tot; i += 256) {
        int f = f9[i];
        pout[s_gbase[f] + (i - s_pref[f])] = pk[i];
    }
}

// One block per FINE bucket (256 nodes), reading its fine-contiguous
// segment (R10/R11-proven structure). Degree histogram (256-way LDS),
// prefix scan, dis, CSR fill -- zero global scattered atomics.
__global__ __launch_bounds__(256) void build_csr(const unsigned* __restrict__ pairs,
                                                 const unsigned* __restrict__ bcnt,
                                                 unsigned* deg, unsigned* row_start,
                                                 float* dis, int* col_src, int N) {
    __shared__ unsigned cnt[256], cur[256], pref2[256];
    __shared__ unsigned s_fb[513];
    __shared__ unsigned wsum[4];
    int b = blockIdx.x, t = threadIdx.x;
    int lane = t & 63;

    // fine bases (512-entry scan, 2/thread)
    {
        unsigned v0 = bcnt[2 * t], v1 = bcnt[2 * t + 1];
        unsigned ps = v0 + v1;
        unsigned s = ps;
#pragma unroll
        for (int off = 1; off < 64; off <<= 1) {
            unsigned u = __shfl_up(s, off, 64);
            if (lane >= off) s += u;
        }
        int w = t >> 6;
        if (lane == 63) wsum[w] = s;
        __syncthreads();
        unsigned woff = 0;
        for (int j = 0; j < w; j++) woff += wsum[j];
        unsigned excl = woff + s - ps;
        s_fb[2 * t] = excl;
        s_fb[2 * t + 1] = excl + v0;
        if (t == 255) s_fb[512] = excl + ps;
    }
    cnt[t] = 0u;
    __syncthreads();
    unsigned lo = s_fb[b], hi = s_fb[b + 1];

    for (unsigned e = lo + t; e < hi; e += 256) {
        unsigned p = pairs[e];
        atomicAdd(&cnt[(p >> 21) & 255u], 1u);
    }
    __syncthreads();

    // 256-entry scan, 1/thread
    unsigned v = cnt[t];
    unsigned s = v;
#pragma unroll
    for (int off = 1; off < 64; off <<= 1) {
        unsigned u = __shfl_up(s, off, 64);
        if (lane >= off) s += u;
    }
    int w = t >> 6;
    if (lane == 63) wsum[w] = s;
    __syncthreads();
    unsigned woff = 0;
    for (int j = 0; j < w; j++) woff += wsum[j];
    pref2[t] = woff + s - v;
    __syncthreads();

    int node = (b << SHIFT_F) + t;
    unsigned rs = lo + pref2[t];
    if (node < N) {
        unsigned c = cnt[t];
        deg[node] = c;
        row_start[node] = rs;
        dis[node] = rsqrtf((float)c + 1.0f);   // +1 self-loop
    }
    cur[t] = rs;
    __syncthreads();
    for (unsigned e = lo + t; e < hi; e += 256) {
        unsigned p = pairs[e];
        unsigned pos = atomicAdd(&cur[(p >> 21) & 255u], 1u);
        col_src[pos] = (int)(p & 0x1FFFFFu);
    }
}

// xps = dis[row] * (x @ W), bf16 MFMA, fp32 x in / packed-bf16 out (pre-scaled).
// W transpose+bf16-convert fused into LDS (padded stride 136 shorts).
// Operand swap: mfma(Wfrag, Xfrag, acc) -> lane holds out[row=rowBase+l15][col=quad*4+reg]
__global__ __launch_bounds__(256) void gemm_xw(const float* __restrict__ x,
                                               const float* __restrict__ W,
                                               const float* __restrict__ dis,
                                               unsigned short* __restrict__ xps, int N) {
    __shared__ unsigned short wt[128 * 136];
    int tid = threadIdx.x;
    for (int idx = tid; idx < DIM * DIM; idx += 256) {
        int k = idx >> 7, n = idx & 127;        // idx = k*128+n -> coalesced W read
        wt[n * 136 + k] = f2bf(W[idx]);
    }
    __syncthreads();

    int wv = tid >> 6, lane = tid & 63;
    int l15 = lane & 15, quad = lane >> 4;
    int rowBase = blockIdx.x * 128 + wv * 32;

    f32x4 acc[2][8];
#pragma unroll
    for (int mt = 0; mt < 2; mt++)
#pragma unroll
        for (int nt = 0; nt < 8; nt++)
            acc[mt][nt] = (f32x4){0.f, 0.f, 0.f, 0.f};

#pragma unroll
    for (int k0 = 0; k0 < DIM; k0 += 32) {
        bf16x8 aa[2], bb[8];
#pragma unroll
        for (int mt = 0; mt < 2; mt++) {
            int r = rowBase + mt * 16 + l15;
            if (r > N - 1) r = N - 1;           // clamp; garbage rows never stored
            const float* xf = x + (size_t)r * DIM + k0 + quad * 8;
            float4 u0 = ((const float4*)xf)[0];
            float4 u1 = ((const float4*)xf)[1];
            bf16x8 a;
            a[0] = (short)f2bf(u0.x); a[1] = (short)f2bf(u0.y);
            a[2] = (short)f2bf(u0.z); a[3] = (short)f2bf(u0.w);
            a[4] = (short)f2bf(u1.x); a[5] = (short)f2bf(u1.y);
            a[6] = (short)f2bf(u1.z); a[7] = (short)f2bf(u1.w);
            aa[mt] = a;
        }
#pragma unroll
        for (int nt = 0; nt < 8; nt++)
            bb[nt] = *(const bf16x8*)(wt + (nt * 16 + l15) * 136 + k0 + quad * 8);
#pragma unroll
        for (int mt = 0; mt < 2; mt++)
#pragma unroll
            for (int nt = 0; nt < 8; nt++)
                acc[mt][nt] = __builtin_amdgcn_mfma_f32_16x16x32_bf16(bb[nt], aa[mt], acc[mt][nt], 0, 0, 0);
    }

#pragma unroll
    for (int mt = 0; mt < 2; mt++) {
        int r = rowBase + mt * 16 + l15;
        if (r < N) {
            float sc = dis[r];                  // pre-scale by source-side dis
#pragma unroll
            for (int nt = 0; nt < 8; nt++) {
                int c0 = nt * 16 + quad * 4;
                ushort4 o;
                o.x = f2bf(acc[mt][nt][0] * sc);
                o.y = f2bf(acc[mt][nt][1] * sc);
                o.z = f2bf(acc[mt][nt][2] * sc);
                o.w = f2bf(acc[mt][nt][3] * sc);
                *(ushort4*)(xps + (size_t)r * DIM + c0) = o;
            }
        }
    }
}

// One wave per node. EXACT R5/R10 form: VGPR=28 -> 8 waves/SIMD; R7 and R9
// ILP variants both regressed -- TLP at max occupancy hides the gather
// latency. Self-loop is virtual slot `cnt`. out[d] = dis[d] * sum(xps).
__global__ __launch_bounds__(256) void aggregate(const unsigned short* __restrict__ xps,
                                                 const unsigned* __restrict__ row_start,
                                                 const unsigned* __restrict__ deg,
                                                 const float* __restrict__ dis,
                                                 const int* __restrict__ col_src,
                                                 float* __restrict__ out, int N) {
    int wid = (int)((blockIdx.x * 256 + threadIdx.x) >> 6);
    if (wid >= N) return;
    int lane = threadIdx.x & 63;
    int grp = lane >> 4, lin = lane & 15;
    const uint4* xp4 = (const uint4*)xps;       // row = 16 x uint4

    float acc[8];
#pragma unroll
    for (int j = 0; j < 8; j++) acc[j] = 0.f;

    unsigned rs = row_start[wid];
    unsigned cnt = deg[wid];
    unsigned tot = cnt + 1;                      // + virtual self slot

    for (unsigned base = 0; base < tot; base += 64) {
        unsigned slot = base + (unsigned)lane;
        int idx = (slot < cnt) ? col_src[rs + slot] : wid;   // invalid/self -> wid (safe)
        unsigned rem = tot - base; if (rem > 64) rem = 64;
        for (unsigned q = 0; q * 8 < rem; q++) {
            unsigned sl0 = q * 8 + (unsigned)grp;
            unsigned sl1 = sl0 + 4;
            int s0 = __shfl(idx, (int)sl0, 64);
            int s1 = __shfl(idx, (int)sl1, 64);
            float m0 = (sl0 < rem) ? 1.f : 0.f;
            float m1 = (sl1 < rem) ? 1.f : 0.f;
            uint4 v0 = xp4[(size_t)s0 * 16 + lin];
            uint4 v1 = xp4[(size_t)s1 * 16 + lin];
            acc[0] = fmaf(bfu_lo(v0.x), m0, acc[0]);
            acc[1] = fmaf(bfu_hi(v0.x), m0, acc[1]);
            acc[2] = fmaf(bfu_lo(v0.y), m0, acc[2]);
            acc[3] = fmaf(bfu_hi(v0.y), m0, acc[3]);
            acc[4] = fmaf(bfu_lo(v0.z), m0, acc[4]);
            acc[5] = fmaf(bfu_hi(v0.z), m0, acc[5]);
            acc[6] = fmaf(bfu_lo(v0.w), m0, acc[6]);
            acc[7] = fmaf(bfu_hi(v0.w), m0, acc[7]);
            acc[0] = fmaf(bfu_lo(v1.x), m1, acc[0]);
            acc[1] = fmaf(bfu_hi(v1.x), m1, acc[1]);
            acc[2] = fmaf(bfu_lo(v1.y), m1, acc[2]);
            acc[3] = fmaf(bfu_hi(v1.y), m1, acc[3]);
            acc[4] = fmaf(bfu_lo(v1.z), m1, acc[4]);
            acc[5] = fmaf(bfu_hi(v1.z), m1, acc[5]);
            acc[6] = fmaf(bfu_lo(v1.w), m1, acc[6]);
            acc[7] = fmaf(bfu_hi(v1.w), m1, acc[7]);
        }
    }

    // reduce across the 4 groups (lanes differing in bits 4 and 5)
#pragma unroll
    for (int j = 0; j < 8; j++) {
        acc[j] += __shfl_xor(acc[j], 16, 64);
        acc[j] += __shfl_xor(acc[j], 32, 64);
    }

    float di = dis[wid];
    if (grp < 2) {                               // 32 lanes store the 512B row
        int jb = (grp & 1) * 4;
        float4 o;
        o.x = acc[jb + 0] * di;
        o.y = acc[jb + 1] * di;
        o.z = acc[jb + 2] * di;
        o.w = acc[jb + 3] * di;
        *(float4*)(out + (size_t)wid * DIM + lin * 8 + jb) = o;
    }
}

extern "C" void kernel_launch(void* const* d_in, const int* in_sizes, int n_in,
                              void* d_out, int out_size, void* d_ws, size_t ws_size,
                              hipStream_t stream) {
    const int N = in_sizes[0] / DIM;
    const int E = in_sizes[1] / 2;
    const float* x = (const float*)d_in[0];                     // fp32 [N][128]
    const void* ei = d_in[1];                                   // int32 or int64 [2][E]
    const float* W = (const float*)d_in[2];                     // fp32 [128][128]
    float* out = (float*)d_out;                                 // fp32 [N][128]

    // Geometry: 512 fine buckets of 256 nodes (valid N<=131072; N=1e5 ok),
    // 64 coarse buckets of 2048 nodes. Packed 21-bit src needs N < 2^21.
    int Bf = (N + (1 << SHIFT_F) - 1) >> SHIFT_F;               // 391

    char* wsp = (char*)d_ws;
    size_t off = 0;
    auto alloc = [&](size_t b) { void* p = wsp + off; off += (b + 255) & ~(size_t)255; return p; };
    unsigned* bcnt   = (unsigned*)alloc(8192);   // [0..511]=fine bcnt, [512..575]=bcur_c, [576..1087]=bcur_f
    unsigned* bcur_c = bcnt + 512;
    unsigned* bcur_f = bcnt + 576;
    int*      flags  = (int*)alloc(256);
    unsigned* deg        = (unsigned*)alloc((size_t)N * 4);
    unsigned* row_start  = (unsigned*)alloc((size_t)N * 4);
    float*    dis        = (float*)alloc((size_t)N * 4);
    int*      col_src    = (int*)alloc((size_t)E * 4);
    unsigned short* xps  = (unsigned short*)alloc((size_t)N * DIM * 2);

    // pout1/pout2 alias the xps region (2*E*4 = 12.8MB <= N*DIM*2 = 25.6MB):
    // dead before gemm_xw writes xps (stream-ordered), so no extra workspace.
    unsigned* pout1 = (unsigned*)xps;
    unsigned* pout2 = pout1 + E;
    if (off + (size_t)2 * E * 4 <= ws_size) {
        pout1 = (unsigned*)alloc((size_t)E * 4);
        pout2 = (unsigned*)alloc((size_t)E * 4);
    }

    hipMemsetAsync(bcnt, 0, 8192, stream);
    hist_detect<<<512, 256, 0, stream>>>(ei, bcnt, flags, E);
    partition1<<<(E + PCH1 - 1) / PCH1, 256, 0, stream>>>(ei, flags, bcnt, bcur_c, pout1, E);
    partition2<<<(E + PCH2 - 1) / PCH2, 256, 0, stream>>>(pout1, bcnt, bcur_f, pout2, E);
    build_csr<<<Bf, 256, 0, stream>>>(pout2, bcnt, deg, row_start, dis, col_src, N);
    gemm_xw<<<(N + 127) / 128, 256, 0, stream>>>(x, W, dis, xps, N);
    aggregate<<<(N + 3) / 4, 256, 0, stream>>>(xps, row_start, deg, dis, col_src, out, N);
}

// Round 14
// 241.832 us; speedup vs baseline: 1.2126x; 1.0338x over previous
//
#include <hip/hip_runtime.h>
#include <hip/hip_bf16.h>

#define DIM 128
#define PCH 4096   // edges per partition block (LDS-staged)

typedef __attribute__((ext_vector_type(8))) short bf16x8;
typedef __attribute__((ext_vector_type(4))) float f32x4;

__device__ __forceinline__ float bfu_lo(unsigned u) { return __uint_as_float(u << 16); }
__device__ __forceinline__ float bfu_hi(unsigned u) { return __uint_as_float(u & 0xffff0000u); }
__device__ __forceinline__ unsigned short f2bf(float f) {
    unsigned u = __float_as_uint(f);
    u += 0x7fffu + ((u >> 16) & 1u);   // round-to-nearest-even
    return (unsigned short)(u >> 16);
}

__device__ __forceinline__ int edge_at(const void* ei, int idx64, long long pos) {
    return idx64 ? (int)__builtin_nontemporal_load((const long long*)ei + pos)
                 : __builtin_nontemporal_load((const int*)ei + pos);
}

// Block-local edge-width sniff: returns 1 iff edge_index is int64 (odd 32-bit
// words -- high halves -- of the first min(E,4096) entries are all zero).
__device__ __forceinline__ int detect_idx64(const void* ei, int E, unsigned* s_or, int* s_flag) {
    const unsigned* ei_w = (const unsigned*)ei;
    int t = threadIdx.x;
    unsigned o = 0;
    int lim = (E < 4096) ? E : 4096;
    for (int k = t; k < lim; k += 256) o |= ei_w[2 * k + 1];
    s_or[t] = o;
    __syncthreads();
    for (int s = 128; s > 0; s >>= 1) {
        if (t < s) s_or[t] |= s_or[t + s];
        __syncthreads();
    }
    if (t == 0) *s_flag = (s_or[0] == 0u) ? 1 : 0;
    __syncthreads();
    return *s_flag;
}

// Bucket histogram of destinations (+fused width detect; block 0 publishes
// the width flag so later passes skip the 16KB sniff). Per-edge increments
// hit LDS; global atomics are only the per-block flush. bcnt pre-zeroed.
__global__ __launch_bounds__(256) void hist_detect(const void* ei, unsigned* bcnt,
                                                   int* flags, int E, int shift) {
    __shared__ unsigned s_h[512];
    __shared__ unsigned s_or[256];
    __shared__ int s_flag;
    int t = threadIdx.x;
    for (int i = t; i < 512; i += 256) s_h[i] = 0u;
    int idx64 = detect_idx64(ei, E, s_or, &s_flag);
    if (blockIdx.x == 0 && t == 0) flags[0] = idx64;
    long long stride = (long long)gridDim.x * 256;
    for (long long e = (long long)blockIdx.x * 256 + t; e < E; e += stride) {
        int d = edge_at(ei, idx64, (long long)E + e);
        atomicAdd(&s_h[d >> shift], 1u);
    }
    __syncthreads();
    for (int i = t; i < 512; i += 256)
        if (s_h[i]) atomicAdd(&bcnt[i], s_h[i]);
}

// LDS-staged partition of raw edges into destination buckets (shift=8,
// B<=512 buckets of 256 nodes). Width flag comes from hist (no per-block
// 16KB sniff). Flush position is computed directly from the staged d
// (no binary search). Best-measured configuration (R10: 243.8us total).
__global__ __launch_bounds__(256) void partition(const void* ei, const int* __restrict__ flags,
                                                 const unsigned* __restrict__ bcnt,
                                                 unsigned* bcur0, long long* pout,
                                                 int E, int B, int shift) {
    __shared__ unsigned s_hist[512], s_off[512], s_gbase[512], s_pref[512], s_bbase[512];
    __shared__ unsigned wsum[4];
    __shared__ long long s_p[PCH];
    int t = threadIdx.x;
    long long base = (long long)blockIdx.x * PCH;
    for (int i = t; i < 512; i += 256) { s_hist[i] = 0u; s_off[i] = 0u; }
    int idx64 = flags[0];

    // local exclusive scan of global bucket counts -> s_bbase
    {
        unsigned v0 = bcnt[2 * t], v1 = bcnt[2 * t + 1];
        unsigned ps = v0 + v1;
        unsigned s = ps;
        int lane = t & 63;
#pragma unroll
        for (int off = 1; off < 64; off <<= 1) {
            unsigned u = __shfl_up(s, off, 64);
            if (lane >= off) s += u;
        }
        int w = t >> 6;
        if (lane == 63) wsum[w] = s;
        __syncthreads();
        unsigned woff = 0;
        for (int j = 0; j < w; j++) woff += wsum[j];
        unsigned excl = woff + s - ps;
        s_bbase[2 * t] = excl;
        s_bbase[2 * t + 1] = excl + v0;
    }
    __syncthreads();

    // load own edges into registers, LDS histogram
    int d_[PCH / 256], s_[PCH / 256];
#pragma unroll
    for (int j = 0; j < PCH / 256; j++) {
        long long e = base + j * 256 + t;
        if (e < E) {
            d_[j] = edge_at(ei, idx64, (long long)E + e);
            s_[j] = edge_at(ei, idx64, e);
            atomicAdd(&s_hist[d_[j] >> shift], 1u);
        } else d_[j] = -1;
    }
    __syncthreads();

    // exclusive scan of local 512 counts -> s_pref
    {
        unsigned v0 = s_hist[2 * t], v1 = s_hist[2 * t + 1];
        unsigned ps = v0 + v1;
        unsigned s = ps;
        int lane = t & 63;
#pragma unroll
        for (int off = 1; off < 64; off <<= 1) {
            unsigned u = __shfl_up(s, off, 64);
            if (lane >= off) s += u;
        }
        int w = t >> 6;
        if (lane == 63) wsum[w] = s;
        __syncthreads();
        unsigned woff = 0;
        for (int j = 0; j < w; j++) woff += wsum[j];
        unsigned excl = woff + s - ps;
        s_pref[2 * t] = excl;
        s_pref[2 * t + 1] = excl + v0;
    }
    __syncthreads();

    for (int i = t; i < B; i += 256)
        if (s_hist[i]) s_gbase[i] = s_bbase[i] + atomicAdd(&bcur0[i], s_hist[i]);
#pragma unroll
    for (int j = 0; j < PCH / 256; j++)
        if (d_[j] >= 0) {
            int b = d_[j] >> shift;
            unsigned p = s_pref[b] + atomicAdd(&s_off[b], 1u);
            s_p[p] = ((long long)s_[j] << 32) | (unsigned)d_[j];
        }
    __syncthreads();
    long long rem = (long long)E - base;
    unsigned tot = (rem < PCH) ? (unsigned)rem : (unsigned)PCH;
    for (unsigned i = t; i < tot; i += 256) {
        long long v = s_p[i];
        int b = ((int)v) >> shift;              // direct bucket recompute (no search)
        pout[s_gbase[b] + (i - s_pref[b])] = v;
    }
}

// One block per bucket (256 nodes). Recomputes bucket bases locally from
// bcnt. Degree histogram, prefix scan, dis, and CSR fill all via LDS
// counters -- zero global scattered atomics.
__global__ __launch_bounds__(256) void build_csr(const long long* __restrict__ pairs,
                                                 const unsigned* __restrict__ bcnt,
                                                 unsigned* deg, unsigned* row_start,
                                                 float* dis, int* col_src,
                                                 int N, int shift) {
    __shared__ unsigned cnt[512], cur[512], pref[512];
    __shared__ unsigned s_bb[513];
    __shared__ unsigned wsum[4];
    int b = blockIdx.x, t = threadIdx.x;
    int npb = 1 << shift;
    if (npb > 512) npb = 512;                   // defensive; caller guarantees <=512
    int nodeLo = b << shift;

    // local exclusive scan of global bucket counts -> bucket [lo,hi)
    {
        unsigned v0 = bcnt[2 * t], v1 = bcnt[2 * t + 1];
        unsigned ps = v0 + v1;
        unsigned s = ps;
        int lane = t & 63;
#pragma unroll
        for (int off = 1; off < 64; off <<= 1) {
            unsigned u = __shfl_up(s, off, 64);
            if (lane >= off) s += u;
        }
        int w = t >> 6;
        if (lane == 63) wsum[w] = s;
        __syncthreads();
        unsigned woff = 0;
        for (int j = 0; j < w; j++) woff += wsum[j];
        unsigned excl = woff + s - ps;
        s_bb[2 * t] = excl;
        s_bb[2 * t + 1] = excl + v0;
        if (t == 255) s_bb[512] = excl + ps;
    }
    __syncthreads();
    unsigned lo = s_bb[b], hi = s_bb[b + 1];

    for (int i = t; i < npb; i += 256) cnt[i] = 0u;
    __syncthreads();
    for (unsigned e = lo + t; e < hi; e += 256) {
        int d = (int)pairs[e];
        atomicAdd(&cnt[d - nodeLo], 1u);
    }
    __syncthreads();
    // exclusive scan of npb (<=512) counts, 2 per thread
    unsigned v0 = (2 * t < npb) ? cnt[2 * t] : 0u;
    unsigned v1 = (2 * t + 1 < npb) ? cnt[2 * t + 1] : 0u;
    unsigned ps = v0 + v1;
    unsigned s = ps;
    int lane = t & 63;
#pragma unroll
    for (int off = 1; off < 64; off <<= 1) {
        unsigned u = __shfl_up(s, off, 64);
        if (lane >= off) s += u;
    }
    int w = t >> 6;
    if (lane == 63) wsum[w] = s;
    __syncthreads();
    unsigned woff = 0;
    for (int j = 0; j < w; j++) woff += wsum[j];
    unsigned excl = woff + s - ps;
    if (2 * t < npb) pref[2 * t] = excl;
    if (2 * t + 1 < npb) pref[2 * t + 1] = excl + v0;
    __syncthreads();
    for (int i = t; i < npb; i += 256) {
        int node = nodeLo + i;
        unsigned rs = lo + pref[i];
        if (node < N) {
            unsigned c = cnt[i];
            deg[node] = c;
            row_start[node] = rs;
            dis[node] = rsqrtf((float)c + 1.0f);   // +1 self-loop
        }
        cur[i] = rs;
    }
    __syncthreads();
    for (unsigned e = lo + t; e < hi; e += 256) {
        long long v = pairs[e];
        int d = (int)v;
        int sv = (int)(v >> 32);
        unsigned pos = atomicAdd(&cur[d - nodeLo], 1u);
        col_src[pos] = sv;
    }
}

// xps = dis[row] * (x @ W), bf16 MFMA, fp32 x in / packed-bf16 out (pre-scaled).
// W transpose+bf16-convert fused into LDS (padded stride 136 shorts).
// Operand swap: mfma(Wfrag, Xfrag, acc) -> lane holds out[row=rowBase+l15][col=quad*4+reg]
__global__ __launch_bounds__(256) void gemm_xw(const float* __restrict__ x,
                                               const float* __restrict__ W,
                                               const float* __restrict__ dis,
                                               unsigned short* __restrict__ xps, int N) {
    __shared__ unsigned short wt[128 * 136];
    int tid = threadIdx.x;
    for (int idx = tid; idx < DIM * DIM; idx += 256) {
        int k = idx >> 7, n = idx & 127;        // idx = k*128+n -> coalesced W read
        wt[n * 136 + k] = f2bf(W[idx]);
    }
    __syncthreads();

    int wv = tid >> 6, lane = tid & 63;
    int l15 = lane & 15, quad = lane >> 4;
    int rowBase = blockIdx.x * 128 + wv * 32;

    f32x4 acc[2][8];
#pragma unroll
    for (int mt = 0; mt < 2; mt++)
#pragma unroll
        for (int nt = 0; nt < 8; nt++)
            acc[mt][nt] = (f32x4){0.f, 0.f, 0.f, 0.f};

#pragma unroll
    for (int k0 = 0; k0 < DIM; k0 += 32) {
        bf16x8 aa[2], bb[8];
#pragma unroll
        for (int mt = 0; mt < 2; mt++) {
            int r = rowBase + mt * 16 + l15;
            if (r > N - 1) r = N - 1;           // clamp; garbage rows never stored
            const float* xf = x + (size_t)r * DIM + k0 + quad * 8;
            float4 u0 = ((const float4*)xf)[0];
            float4 u1 = ((const float4*)xf)[1];
            bf16x8 a;
            a[0] = (short)f2bf(u0.x); a[1] = (short)f2bf(u0.y);
            a[2] = (short)f2bf(u0.z); a[3] = (short)f2bf(u0.w);
            a[4] = (short)f2bf(u1.x); a[5] = (short)f2bf(u1.y);
            a[6] = (short)f2bf(u1.z); a[7] = (short)f2bf(u1.w);
            aa[mt] = a;
        }
#pragma unroll
        for (int nt = 0; nt < 8; nt++)
            bb[nt] = *(const bf16x8*)(wt + (nt * 16 + l15) * 136 + k0 + quad * 8);
#pragma unroll
        for (int mt = 0; mt < 2; mt++)
#pragma unroll
            for (int nt = 0; nt < 8; nt++)
                acc[mt][nt] = __builtin_amdgcn_mfma_f32_16x16x32_bf16(bb[nt], aa[mt], acc[mt][nt], 0, 0, 0);
    }

#pragma unroll
    for (int mt = 0; mt < 2; mt++) {
        int r = rowBase + mt * 16 + l15;
        if (r < N) {
            float sc = dis[r];                  // pre-scale by source-side dis
#pragma unroll
            for (int nt = 0; nt < 8; nt++) {
                int c0 = nt * 16 + quad * 4;
                ushort4 o;
                o.x = f2bf(acc[mt][nt][0] * sc);
                o.y = f2bf(acc[mt][nt][1] * sc);
                o.z = f2bf(acc[mt][nt][2] * sc);
                o.w = f2bf(acc[mt][nt][3] * sc);
                *(ushort4*)(xps + (size_t)r * DIM + c0) = o;
            }
        }
    }
}

// One wave per node. 16 lanes per edge row (uint4 = 16B = 8 bf16 each), 4 edge
// slots per wave, inner loop unrolled x2 (8 slots / iter). Indices are
// prefetched 64-at-a-time (one coalesced load) and shfl-broadcast.
// EXACT R5 form: VGPR=28 -> 8 waves/SIMD; R7 (16-deep batch, VGPR 68) and
// R9 (depth-2 prefetch, VGPR 44) both REGRESSED -- TLP at max occupancy is
// what hides the random-gather latency, not per-wave ILP. FETCH ~193MB =
// 8 XCDs x 25.6MB xps (per-XCD compulsory stream) at ~3.9 TB/s = the
// random-256B-gather service ceiling for this pattern.
// Self-loop is virtual slot `cnt` (index wid). out[d] = dis[d] * sum(xps).
__global__ __launch_bounds__(256) void aggregate(const unsigned short* __restrict__ xps,
                                                 const unsigned* __restrict__ row_start,
                                                 const unsigned* __restrict__ deg,
                                                 const float* __restrict__ dis,
                                                 const int* __restrict__ col_src,
                                                 float* __restrict__ out, int N) {
    int wid = (int)((blockIdx.x * 256 + threadIdx.x) >> 6);
    if (wid >= N) return;
    int lane = threadIdx.x & 63;
    int grp = lane >> 4, lin = lane & 15;
    const uint4* xp4 = (const uint4*)xps;       // row = 16 x uint4

    float acc[8];
#pragma unroll
    for (int j = 0; j < 8; j++) acc[j] = 0.f;

    unsigned rs = row_start[wid];
    unsigned cnt = deg[wid];
    unsigned tot = cnt + 1;                      // + virtual self slot

    for (unsigned base = 0; base < tot; base += 64) {
        unsigned slot = base + (unsigned)lane;
        int idx = (slot < cnt) ? col_src[rs + slot] : wid;   // invalid/self -> wid (safe)
        unsigned rem = tot - base; if (rem > 64) rem = 64;
        for (unsigned q = 0; q * 8 < rem; q++) {
            unsigned sl0 = q * 8 + (unsigned)grp;
            unsigned sl1 = sl0 + 4;
            int s0 = __shfl(idx, (int)sl0, 64);
            int s1 = __shfl(idx, (int)sl1, 64);
            float m0 = (sl0 < rem) ? 1.f : 0.f;
            float m1 = (sl1 < rem) ? 1.f : 0.f;
            uint4 v0 = xp4[(size_t)s0 * 16 + lin];
            uint4 v1 = xp4[(size_t)s1 * 16 + lin];
            acc[0] = fmaf(bfu_lo(v0.x), m0, acc[0]);
            acc[1] = fmaf(bfu_hi(v0.x), m0, acc[1]);
            acc[2] = fmaf(bfu_lo(v0.y), m0, acc[2]);
            acc[3] = fmaf(bfu_hi(v0.y), m0, acc[3]);
            acc[4] = fmaf(bfu_lo(v0.z), m0, acc[4]);
            acc[5] = fmaf(bfu_hi(v0.z), m0, acc[5]);
            acc[6] = fmaf(bfu_lo(v0.w), m0, acc[6]);
            acc[7] = fmaf(bfu_hi(v0.w), m0, acc[7]);
            acc[0] = fmaf(bfu_lo(v1.x), m1, acc[0]);
            acc[1] = fmaf(bfu_hi(v1.x), m1, acc[1]);
            acc[2] = fmaf(bfu_lo(v1.y), m1, acc[2]);
            acc[3] = fmaf(bfu_hi(v1.y), m1, acc[3]);
            acc[4] = fmaf(bfu_lo(v1.z), m1, acc[4]);
            acc[5] = fmaf(bfu_hi(v1.z), m1, acc[5]);
            acc[6] = fmaf(bfu_lo(v1.w), m1, acc[6]);
            acc[7] = fmaf(bfu_hi(v1.w), m1, acc[7]);
        }
    }

    // reduce across the 4 groups (lanes differing in bits 4 and 5)
#pragma unroll
    for (int j = 0; j < 8; j++) {
        acc[j] += __shfl_xor(acc[j], 16, 64);
        acc[j] += __shfl_xor(acc[j], 32, 64);
    }

    float di = dis[wid];
    if (grp < 2) {                               // 32 lanes store the 512B row
        int jb = (grp & 1) * 4;
        float4 o;
        o.x = acc[jb + 0] * di;
        o.y = acc[jb + 1] * di;
        o.z = acc[jb + 2] * di;
        o.w = acc[jb + 3] * di;
        *(float4*)(out + (size_t)wid * DIM + lin * 8 + jb) = o;
    }
}

extern "C" void kernel_launch(void* const* d_in, const int* in_sizes, int n_in,
                              void* d_out, int out_size, void* d_ws, size_t ws_size,
                              hipStream_t stream) {
    const int N = in_sizes[0] / DIM;
    const int E = in_sizes[1] / 2;
    const float* x = (const float*)d_in[0];                     // fp32 [N][128]
    const void* ei = d_in[1];                                   // int32 or int64 [2][E]
    const float* W = (const float*)d_in[2];                     // fp32 [128][128]
    float* out = (float*)d_out;                                 // fp32 [N][128]

    // bucket geometry: 256 nodes per bucket (shift=8), B <= 512 buckets.
    // R8 lesson: coarse buckets starve build_csr's grid; B ~ 1.5x CU count.
    int shift = 8;
    while ((((long long)N + (1LL << shift) - 1) >> shift) > 512 && shift < 9) shift++;
    int B = (int)(((long long)N + (1LL << shift) - 1) >> shift);

    char* wsp = (char*)d_ws;
    size_t off = 0;
    auto alloc = [&](size_t b) { void* p = wsp + off; off += (b + 255) & ~(size_t)255; return p; };
    unsigned* bcnt       = (unsigned*)alloc(4096);              // [0..511]=bcnt, [512..1023]=bcur0
    unsigned* bcur0      = bcnt + 512;
    int*      flags      = (int*)alloc(256);
    unsigned* deg        = (unsigned*)alloc((size_t)N * 4);
    unsigned* row_start  = (unsigned*)alloc((size_t)N * 4);
    float*    dis        = (float*)alloc((size_t)N * 4);
    int*      col_src    = (int*)alloc((size_t)E * 4);
    unsigned short* xps  = (unsigned short*)alloc((size_t)N * DIM * 2);

    // pairs alias the xps region (E*8 = 12.8MB <= N*DIM*2 = 25.6MB): dead
    // before gemm_xw writes xps (stream-ordered), so no extra workspace.
    long long* pairs = (long long*)xps;
    if ((size_t)E * 8 > (size_t)N * DIM * 2 && off + (size_t)E * 8 <= ws_size)
        pairs = (long long*)alloc((size_t)E * 8);

    hipMemsetAsync(bcnt, 0, 4096, stream);
    hist_detect<<<512, 256, 0, stream>>>(ei, bcnt, flags, E, shift);
    partition<<<(E + PCH - 1) / PCH, 256, 0, stream>>>(ei, flags, bcnt, bcur0, pairs, E, B, shift);
    build_csr<<<B, 256, 0, stream>>>(pairs, bcnt, deg, row_start, dis, col_src, N, shift);
    gemm_xw<<<(N + 127) / 128, 256, 0, stream>>>(x, W, dis, xps, N);
    aggregate<<<(N + 3) / 4, 256, 0, stream>>>(xps, row_start, deg, dis, col_src, out, N);
}